// Round 4
// baseline (148.890 us; speedup 1.0000x reference)
//
#include <hip/hip_runtime.h>

// image (1,1024,1024) f32, x (16,1,1024,1024) f32, W_KL (9,1,3,3) f32, b_KL (9,) f32.
// y[b,h,w] = sum_{a,d} (conv(image,W_KL)[a*3+d][h,w] + b[a*3+d]) * x[b,h+a-1,w+d-1]
#define IH 1024
#define IW 1024
#define NB 16
#define BPB 4      // batches per block
#define TW 256     // tile width (outputs)
#define TH 4       // tile height (outputs)
#define LROWS 6    // TH + 2 halo rows
#define LW 272     // LDS row words: w in [W0-8, W0+264)  (float4-aligned both ends)

typedef float v4f __attribute__((ext_vector_type(4)));

// Block 64x4 = 256 threads. Thread (tx,ty): 4 px at row H0+ty, w0 = W0+4*tx.
// Grid (1024/256, 1024/4, 16/4) = (4, 256, 4) = 4096 blocks.
__global__ __launch_bounds__(256) void fused_smblock(
    const float* __restrict__ image,
    const float* __restrict__ x,
    const float* __restrict__ Wk,
    const float* __restrict__ bk,
    float* __restrict__ out)
{
    __shared__ float tile[LROWS * LW];

    const int tx = threadIdx.x;            // 0..63 (one wave = one ty row)
    const int ty = threadIdx.y;            // 0..3
    const int W0 = blockIdx.x * TW;
    const int H0 = blockIdx.y * TH;

    // ---- stage one plane's 6 halo rows into LDS: pure coalesced float4 loads ----
    auto stage = [&](const float* __restrict__ plane) {
#pragma unroll
        for (int r = ty; r < LROWS; r += TH) {          // ty -> rows {ty, ty+4<6}
            const int hh = H0 - 1 + r;
            const bool rowok = (hh >= 0) && (hh < IH);
            const float* rowp = plane + (size_t)(rowok ? hh : 0) * IW;
#pragma unroll
            for (int c = tx; c < LW / 4; c += 64) {     // 68 float4 per row
                const int w = W0 - 8 + c * 4;           // global col of elem 0
                v4f v = {0.f, 0.f, 0.f, 0.f};
                if (rowok && w >= 0 && w + 3 < IW) {
                    v = *(const v4f*)(rowp + w);
                } else if (rowok) {
                    float* vv = (float*)&v;
#pragma unroll
                    for (int j = 0; j < 4; ++j) {
                        const int wj = w + j;
                        vv[j] = (wj >= 0 && wj < IW) ? rowp[wj] : 0.f;
                    }
                }
                *(v4f*)&tile[r * LW + c * 4] = v;
            }
        }
    };

    // ---- conflict-free window read: o[0..5] = row r, w0-1 .. w0+4 ----
    // words L = 4tx+6 .. 4tx+13 via 4x ds_read_b64 (lane stride 4 words,
    // 2 words/lane -> all 32 banks, no conflict). w0-1 <-> L=4tx+7.
    auto window6 = [&](int r, float o[6]) {
        const float2* base = (const float2*)&tile[r * LW + 4 * tx + 6];
        const float2 d0 = base[0], d1 = base[1], d2 = base[2], d3 = base[3];
        o[0] = d0.y; o[1] = d1.x; o[2] = d1.y; o[3] = d2.x; o[4] = d2.y; o[5] = d3.x;
    };

    // conv weights / bias (uniform -> scalar loads)
    float wk[81];
#pragma unroll
    for (int i = 0; i < 81; ++i) wk[i] = Wk[i];
    float bb[9];
#pragma unroll
    for (int c = 0; c < 9; ++c) bb[c] = bk[c];

    // ---- K phase: stage image tile, compute per-pixel kernels (once, reused BPB x) ----
    stage(image);
    __syncthreads();
    float Kv[4][9];
    {
        float p[3][6];
#pragma unroll
        for (int a = 0; a < 3; ++a) window6(ty + a, p[a]);
#pragma unroll
        for (int j = 0; j < 4; ++j)
#pragma unroll
            for (int c = 0; c < 9; ++c) {
                float acc = bb[c];
#pragma unroll
                for (int i = 0; i < 3; ++i)
#pragma unroll
                    for (int jj = 0; jj < 3; ++jj)
                        acc = fmaf(wk[c * 9 + i * 3 + jj], p[i][j + jj], acc);
                Kv[j][c] = acc;
            }
    }

    // ---- apply phase: BPB batches through the same LDS buffer ----
    const size_t plane = (size_t)IH * IW;
    const int b0 = blockIdx.z * BPB;
    for (int bi = 0; bi < BPB; ++bi) {
        __syncthreads();                       // LDS consumed by previous phase
        stage(x + (size_t)(b0 + bi) * plane);
        __syncthreads();
        float r3[3][6];
#pragma unroll
        for (int a = 0; a < 3; ++a) window6(ty + a, r3[a]);
        float yv[4];
#pragma unroll
        for (int j = 0; j < 4; ++j) {
            float acc = 0.f;
#pragma unroll
            for (int a = 0; a < 3; ++a)
#pragma unroll
                for (int d = 0; d < 3; ++d)
                    acc = fmaf(Kv[j][a * 3 + d], r3[a][j + d], acc);
            yv[j] = acc;
        }
        v4f yvec; yvec.x = yv[0]; yvec.y = yv[1]; yvec.z = yv[2]; yvec.w = yv[3];
        __builtin_nontemporal_store(
            yvec, (v4f*)(out + (size_t)(b0 + bi) * plane + (size_t)(H0 + ty) * IW
                         + W0 + 4 * tx));
    }
}

extern "C" void kernel_launch(void* const* d_in, const int* in_sizes, int n_in,
                              void* d_out, int out_size, void* d_ws, size_t ws_size,
                              hipStream_t stream) {
    const float* image = (const float*)d_in[0]; // 1*1024*1024
    const float* x     = (const float*)d_in[1]; // 16*1*1024*1024
    const float* Wk    = (const float*)d_in[2]; // 9*1*3*3
    const float* bk    = (const float*)d_in[3]; // 9
    float* out = (float*)d_out;                 // 16*1024*1024 f32

    dim3 block(64, TH);
    dim3 grid(IW / TW, IH / TH, NB / BPB);      // (4, 256, 4)
    fused_smblock<<<grid, block, 0, stream>>>(image, x, Wk, bk, out);
}

// Round 10
// 138.927 us; speedup vs baseline: 1.0717x; 1.0717x over previous
//
#include <hip/hip_runtime.h>

// image (1,1024,1024) f32, x (16,1,1024,1024) f32, W_KL (9,1,3,3) f32, b_KL (9,) f32.
// y[b,h,w] = sum_{a,d} (conv(image,W_KL)[a*3+d][h,w] + b[a*3+d]) * x[b,h+a-1,w+d-1]
#define IH 1024
#define IW 1024
#define NB 16

typedef float v4f __attribute__((ext_vector_type(4)));
typedef float v2f __attribute__((ext_vector_type(2)));

// Load the 3x6 window for 4 output px at (h, w0..w0+3) into win[3][6]:
// win[a][j] = plane[h+a-1][w0-1+j], zero-padded. Aligned vector loads only.
__device__ __forceinline__ void load_win(const float* __restrict__ plane,
                                         int h, int w0, float win[3][6]) {
#pragma unroll
    for (int a = 0; a < 3; ++a) {
        const int hh = h + a - 1;
        const bool rowok = (hh >= 0) & (hh < IH);
        const float* rowp = plane + (size_t)(rowok ? hh : 0) * IW;
        const v2f lv = *(const v2f*)(rowp + (w0 > 0 ? w0 - 2 : 0));      // [w0-2,w0-1]
        const v4f mv = *(const v4f*)(rowp + w0);                          // [w0..w0+3]
        const v2f rv = *(const v2f*)(rowp + (w0 + 4 < IW ? w0 + 4 : IW - 2)); // [w0+4,w0+5]
        const float fl = (rowok && w0 > 0)       ? lv.y : 0.f;
        const float fr = (rowok && w0 + 4 < IW)  ? rv.x : 0.f;
        win[a][0] = fl;
        win[a][1] = rowok ? mv.x : 0.f;
        win[a][2] = rowok ? mv.y : 0.f;
        win[a][3] = rowok ? mv.z : 0.f;
        win[a][4] = rowok ? mv.w : 0.f;
        win[a][5] = fr;
    }
}

// Block 64x4 = 256 thr; thread: 4 px at (h, w0..w0+3), all 16 batches,
// software-pipelined (prefetch batch b+1's window while computing batch b).
// Grid (1024/256, 1024/4) = (4,256) = 1024 blocks.
__global__ __launch_bounds__(256) void fused_smblock(
    const float* __restrict__ image,
    const float* __restrict__ x,
    const float* __restrict__ Wk,
    const float* __restrict__ bk,
    float* __restrict__ out)
{
    const int tx = threadIdx.x;               // 0..63
    const int ty = threadIdx.y;               // 0..3
    const int w0 = blockIdx.x * 256 + tx * 4; // float4-aligned
    const int h  = blockIdx.y * 4 + ty;

    // conv weights / bias: uniform addresses -> scalar loads (SGPRs)
    float wk[81];
#pragma unroll
    for (int i = 0; i < 81; ++i) wk[i] = Wk[i];
    float bb[9];
#pragma unroll
    for (int c = 0; c < 9; ++c) bb[c] = bk[c];

    // ---- K phase: per-pixel kernels from image (once, amortized over 16 batches) ----
    float p[3][6];
    load_win(image, h, w0, p);
    float Kv[4][9];
#pragma unroll
    for (int j = 0; j < 4; ++j)
#pragma unroll
        for (int c = 0; c < 9; ++c) {
            float acc = bb[c];
#pragma unroll
            for (int a = 0; a < 3; ++a)
#pragma unroll
                for (int d = 0; d < 3; ++d)
                    acc = fmaf(wk[c * 9 + a * 3 + d], p[a][j + d], acc);
            Kv[j][c] = acc;
        }

    // ---- apply phase: depth-2 register pipeline over 16 batches ----
    const size_t plane = (size_t)IH * IW;
    const size_t obase = (size_t)h * IW + w0;

    float buf[2][3][6];
    load_win(x, h, w0, buf[0]);               // batch 0 in flight
#pragma unroll 2
    for (int b = 0; b < NB; ++b) {
        if (b + 1 < NB)                       // issue batch b+1's loads first
            load_win(x + (size_t)(b + 1) * plane, h, w0, buf[(b + 1) & 1]);
        const float (*r3)[6] = buf[b & 1];    // consume batch b
        v4f y;
#pragma unroll
        for (int j = 0; j < 4; ++j) {
            float acc = 0.f;
#pragma unroll
            for (int a = 0; a < 3; ++a)
#pragma unroll
                for (int d = 0; d < 3; ++d)
                    acc = fmaf(Kv[j][a * 3 + d], r3[a][j + d], acc);
            y[j] = acc;
        }
        __builtin_nontemporal_store(y, (v4f*)(out + (size_t)b * plane + obase));
    }
}

extern "C" void kernel_launch(void* const* d_in, const int* in_sizes, int n_in,
                              void* d_out, int out_size, void* d_ws, size_t ws_size,
                              hipStream_t stream) {
    const float* image = (const float*)d_in[0]; // 1*1024*1024
    const float* x     = (const float*)d_in[1]; // 16*1*1024*1024
    const float* Wk    = (const float*)d_in[2]; // 9*1*3*3
    const float* bk    = (const float*)d_in[3]; // 9
    float* out = (float*)d_out;                 // 16*1024*1024 f32

    dim3 block(64, 4);
    dim3 grid(IW / 256, IH / 4);                // (4, 256) = 1024 blocks
    fused_smblock<<<grid, block, 0, stream>>>(image, x, Wk, bk, out);
}